// Round 1
// baseline (419.265 us; speedup 1.0000x reference)
//
#include <hip/hip_runtime.h>
#include <math.h>

// CLAHE3D: B=C=1, D=H=W=128, GRID=8x8x8 (tiles 16^3, vpt=4096, nt=512), NB=64,
// bandwidth=0.001, clip=4.0 -> limit=256.
//
// ws layout (floats):
//   M      [128][8]          offset 0        (1024)   axis spline matrix (same for d/h/w)
//   cdfbuf [64][8][8][8]     offset 1024     (32768)  per-tile CDF, [n][ti][tj][tk]
//   T1w    [128][64][8][8]   offset 33792    (524288) after w-axis fold, [w][n][i][j]
//   minmax [2]               offset 558080   (2)

#define WS_M      0
#define WS_CDF    1024
#define WS_T1     (1024 + 32768)
#define WS_MM     (1024 + 32768 + 524288)

__device__ __forceinline__ float bspline5(float x) {
    float t = fabsf(x);
    float t2 = t * t, t3 = t2 * t, t4 = t2 * t2, t5 = t4 * t;
    float w0 = 11.0f/20.0f - t2*0.5f + t4*0.25f - t5*(1.0f/12.0f);
    float w1 = 17.0f/40.0f + t*(5.0f/8.0f) - t2*(7.0f/4.0f) + t3*(5.0f/4.0f)
             - t4*(3.0f/8.0f) + t5*(1.0f/24.0f);
    float u = 3.0f - t;
    float w2 = u*u*u*u*u*(1.0f/120.0f);
    return t < 1.0f ? w0 : (t < 2.0f ? w1 : (t < 3.0f ? w2 : 0.0f));
}

// reflect (dct2) boundary for g=8 (period 16): taps in [-3, 10]
__device__ __forceinline__ int reflect16(int t) {
    int r = t & 15;             // == ((t % 16) + 16) % 16 for two's complement
    return r < 8 ? r : 15 - r;
}

// ---------- k0: axis matrix M[128][8] + init minmax ----------
__global__ void k0_axis(float* __restrict__ M, float* __restrict__ minmax) {
    int s = threadIdx.x;  // 0..127
    if (s == 0) { minmax[0] = __int_as_float(0x7f7fffff); minmax[1] = 0.0f; }
    const float step = 8.0625f / 127.0f;            // linspace(-0.53125, 7.53125, 128)
    float c = -0.53125f + (float)s * step;
    float row[8];
    #pragma unroll
    for (int i = 0; i < 8; ++i) row[i] = 0.0f;
    int base = (int)floorf(c) - 2;
    for (int t = 0; t < 6; ++t) {
        int tap = base + t;
        float w = bspline5(c - (float)tap);
        row[reflect16(tap)] += w;
    }
    #pragma unroll
    for (int i = 0; i < 8; ++i) M[s * 8 + i] = row[i];
}

// ---------- k1: per-tile KDE histogram -> clip/redistribute -> CDF ----------
__global__ __launch_bounds__(256) void k1_hist(const float* __restrict__ x,
                                               float* __restrict__ cdfbuf) {
    __shared__ float hist[64];
    int t = threadIdx.x;
    int tile = blockIdx.x;                          // ti*64 + tj*8 + tk
    int ti = tile >> 6, tj = (tile >> 3) & 7, tk = tile & 7;
    if (t < 64) hist[t] = 0.0f;
    __syncthreads();

    const float inv63 = 1.0f / 63.0f;
    int gbase = ((ti * 16) * 128 + tj * 16) * 128 + tk * 16;
    for (int it = 0; it < 16; ++it) {
        int v = it * 256 + t;                       // tile-linear: a=v>>8, b=(v>>4)&15, c=v&15
        int a = v >> 8, b = (v >> 4) & 15, cc = v & 15;
        float val = x[gbase + (a * 128 + b) * 128 + cc];
        float bc = val * 63.0f;
        int b0 = (int)floorf(bc + 0.5f);
        #pragma unroll
        for (int dbi = -1; dbi <= 1; ++dbi) {
            int bi = b0 + dbi;
            if (bi < 0 || bi > 63) continue;
            float q = (val - (float)bi * inv63) * 1000.0f;   // /bandwidth
            float w = expf(-0.5f * q * q);
            if (w != 0.0f) atomicAdd(&hist[bi], w);
        }
    }
    __syncthreads();

    if (t < 64) {                                   // one wave handles the 64 bins
        float pdf = hist[t] * (1.0f / 4096.0f);     // mean over vpt
        float s = pdf;
        #pragma unroll
        for (int off = 32; off >= 1; off >>= 1) s += __shfl_xor(s, off, 64);
        float pdfn = pdf / (s + 1e-10f);
        float histo = fminf(pdfn * 4096.0f, 256.0f);    // clip at limit
        float s2 = histo;
        #pragma unroll
        for (int off = 32; off >= 1; off >>= 1) s2 += __shfl_xor(s2, off, 64);
        float clipped = 4096.0f - s2;
        // jnp.remainder(clipped, 64) = clipped - floor(clipped/64)*64
        float residual = clipped - floorf(clipped * (1.0f / 64.0f)) * 64.0f;
        float redist = (clipped - residual) * (1.0f / 64.0f);
        float h2 = histo + redist + (((float)t < residual) ? 1.0f : 0.0f);
        // inclusive prefix sum over 64 lanes
        float cum = h2;
        #pragma unroll
        for (int off = 1; off < 64; off <<= 1) {
            float p = __shfl_up(cum, off, 64);
            if (t >= off) cum += p;
        }
        cdfbuf[t * 512 + tile] = cum * (63.0f / 4096.0f);
    }
}

// ---------- k2: fold w-axis: T1w[w][n][i][j] = sum_k cdf[n][i][j][k] * M[w][k] ----------
__global__ __launch_bounds__(256) void k2_t1(const float* __restrict__ cdfbuf,
                                             const float* __restrict__ M,
                                             float* __restrict__ T1w) {
    int idx = blockIdx.x * 256 + threadIdx.x;       // 524288 = 128 * 4096
    int w = idx >> 12;
    int o = idx & 4095;                             // (n,i,j) linear
    const float* c = cdfbuf + o * 8;
    const float* m = M + w * 8;
    float s = 0.0f;
    #pragma unroll
    for (int k = 0; k < 8; ++k) s += c[k] * m[k];
    T1w[idx] = s;
}

// ---------- k3: per-(h,w) column: fold j -> t2[n][i] in LDS, then per-d bin spline ----------
__global__ __launch_bounds__(128) void k3_final(const float* __restrict__ x,
                                                const float* __restrict__ T1w,
                                                const float* __restrict__ M,
                                                float* __restrict__ out,
                                                float* __restrict__ minmax) {
    __shared__ float t2[512];                       // [n][i]
    __shared__ float red[4];
    int tid = threadIdx.x;                          // = d
    int h = blockIdx.x >> 7;
    int w = blockIdx.x & 127;

    float MH[8];
    #pragma unroll
    for (int j = 0; j < 8; ++j) MH[j] = M[h * 8 + j];

    const float* T1s = T1w + w * 4096;              // contiguous 16 KB slice
    #pragma unroll
    for (int p = 0; p < 4; ++p) {
        int o2 = p * 128 + tid;                     // n*8 + i
        float s = 0.0f;
        #pragma unroll
        for (int j = 0; j < 8; ++j) s += T1s[o2 * 8 + j] * MH[j];
        t2[o2] = s;
    }

    float MD[8];
    #pragma unroll
    for (int i = 0; i < 8; ++i) MD[i] = M[tid * 8 + i];
    __syncthreads();

    float v = x[(tid * 128 + h) * 128 + w];
    float cb = v * 63.0f;
    int basei = (int)floorf(cb) - 2;
    float acc = 0.0f;
    #pragma unroll
    for (int tt = 0; tt < 6; ++tt) {
        int tap = basei + tt;                       // in [-2, 66]
        float wb = bspline5(cb - (float)tap);
        int r = tap & 127;                          // reflect period 128
        int idx = r < 64 ? r : 127 - r;
        const float* t2r = &t2[idx * 8];
        float s = 0.0f;
        #pragma unroll
        for (int i = 0; i < 8; ++i) s += MD[i] * t2r[i];
        acc += wb * s;
    }
    out[(tid * 128 + h) * 128 + w] = acc;

    // block min/max -> global atomics (values are non-negative)
    float mn = acc, mx = acc;
    #pragma unroll
    for (int off = 32; off >= 1; off >>= 1) {
        mn = fminf(mn, __shfl_xor(mn, off, 64));
        mx = fmaxf(mx, __shfl_xor(mx, off, 64));
    }
    int lane = tid & 63, wv = tid >> 6;
    if (lane == 0) { red[wv * 2] = mn; red[wv * 2 + 1] = mx; }
    __syncthreads();
    if (tid == 0) {
        mn = fminf(red[0], red[2]);
        mx = fmaxf(red[1], red[3]);
        atomicMin((int*)&minmax[0], __float_as_int(mn));
        atomicMax((int*)&minmax[1], __float_as_int(mx));
    }
}

// ---------- k4: global min-max normalize (in place) ----------
__global__ __launch_bounds__(256) void k4_norm(float* __restrict__ out,
                                               const float* __restrict__ minmax) {
    int idx = blockIdx.x * 256 + threadIdx.x;       // 524288 float4
    float mn = minmax[0], mx = minmax[1];
    float sc = 1.0f / (mx - mn + 1e-10f);
    float4* o4 = (float4*)out;
    float4 val = o4[idx];
    val.x = (val.x - mn) * sc;
    val.y = (val.y - mn) * sc;
    val.z = (val.z - mn) * sc;
    val.w = (val.w - mn) * sc;
    o4[idx] = val;
}

extern "C" void kernel_launch(void* const* d_in, const int* in_sizes, int n_in,
                              void* d_out, int out_size, void* d_ws, size_t ws_size,
                              hipStream_t stream) {
    const float* x = (const float*)d_in[0];
    float* out = (float*)d_out;
    float* ws = (float*)d_ws;
    float* M      = ws + WS_M;
    float* cdfbuf = ws + WS_CDF;
    float* T1w    = ws + WS_T1;
    float* minmax = ws + WS_MM;

    hipLaunchKernelGGL(k0_axis, dim3(1),     dim3(128), 0, stream, M, minmax);
    hipLaunchKernelGGL(k1_hist, dim3(512),   dim3(256), 0, stream, x, cdfbuf);
    hipLaunchKernelGGL(k2_t1,   dim3(2048),  dim3(256), 0, stream, cdfbuf, M, T1w);
    hipLaunchKernelGGL(k3_final,dim3(16384), dim3(128), 0, stream, x, T1w, M, out, minmax);
    hipLaunchKernelGGL(k4_norm, dim3(2048),  dim3(256), 0, stream, out, minmax);
}

// Round 2
// 417.321 us; speedup vs baseline: 1.0047x; 1.0047x over previous
//
#include <hip/hip_runtime.h>
#include <math.h>

// CLAHE3D: B=C=1, D=H=W=128, GRID=8x8x8 (tiles 16^3, vpt=4096, nt=512), NB=64,
// bandwidth=0.001, clip=4.0 -> limit=256.
//
// ws layout (floats):
//   M      [128][8]          offset 0        (1024)   axis spline matrix (same for d/h/w)
//   cdfbuf [64][8][8][8]     offset 1024     (32768)  per-tile CDF, [n][i][j][k] (i=D,j=H,k=W)
//   T1d    [128][64][8][8]   offset 33792    (524288) d-axis fold: [d][n][j][k]
//   minmax [2]               offset 558080   (2)

#define WS_M      0
#define WS_CDF    1024
#define WS_T1D    (1024 + 32768)
#define WS_MM     (1024 + 32768 + 524288)

__device__ __forceinline__ float bspline5(float x) {
    float t = fabsf(x);
    float t2 = t * t, t3 = t2 * t, t4 = t2 * t2, t5 = t4 * t;
    float w0 = 11.0f/20.0f - t2*0.5f + t4*0.25f - t5*(1.0f/12.0f);
    float w1 = 17.0f/40.0f + t*(5.0f/8.0f) - t2*(7.0f/4.0f) + t3*(5.0f/4.0f)
             - t4*(3.0f/8.0f) + t5*(1.0f/24.0f);
    float u = 3.0f - t;
    float w2 = u*u*u*u*u*(1.0f/120.0f);
    return t < 1.0f ? w0 : (t < 2.0f ? w1 : (t < 3.0f ? w2 : 0.0f));
}

// reflect (dct2) boundary for g=8 (period 16): taps in [-3, 10]
__device__ __forceinline__ int reflect16(int t) {
    int r = t & 15;
    return r < 8 ? r : 15 - r;
}

// ---------- k0: axis matrix M[128][8] + init minmax ----------
__global__ void k0_axis(float* __restrict__ M, float* __restrict__ minmax) {
    int s = threadIdx.x;  // 0..127
    if (s == 0) { minmax[0] = __int_as_float(0x7f7fffff); minmax[1] = 0.0f; }
    const float step = 8.0625f / 127.0f;            // linspace(-0.53125, 7.53125, 128)
    float c = -0.53125f + (float)s * step;
    float row[8];
    #pragma unroll
    for (int i = 0; i < 8; ++i) row[i] = 0.0f;
    int base = (int)floorf(c) - 2;
    for (int t = 0; t < 6; ++t) {
        int tap = base + t;
        float w = bspline5(c - (float)tap);
        row[reflect16(tap)] += w;
    }
    #pragma unroll
    for (int i = 0; i < 8; ++i) M[s * 8 + i] = row[i];
}

// ---------- k1: per-tile KDE histogram -> clip/redistribute -> CDF ----------
__global__ __launch_bounds__(256) void k1_hist(const float* __restrict__ x,
                                               float* __restrict__ cdfbuf) {
    __shared__ float hist[64];
    int t = threadIdx.x;
    int tile = blockIdx.x;                          // ti*64 + tj*8 + tk
    int ti = tile >> 6, tj = (tile >> 3) & 7, tk = tile & 7;
    if (t < 64) hist[t] = 0.0f;
    __syncthreads();

    const float inv63 = 1.0f / 63.0f;
    int gbase = ((ti * 16) * 128 + tj * 16) * 128 + tk * 16;
    for (int it = 0; it < 16; ++it) {
        int v = it * 256 + t;                       // tile-linear: a=v>>8, b=(v>>4)&15, c=v&15
        int a = v >> 8, b = (v >> 4) & 15, cc = v & 15;
        float val = x[gbase + (a * 128 + b) * 128 + cc];
        float bc = val * 63.0f;
        int b0 = (int)floorf(bc + 0.5f);
        #pragma unroll
        for (int dbi = -1; dbi <= 1; ++dbi) {
            int bi = b0 + dbi;
            if (bi < 0 || bi > 63) continue;
            float q = (val - (float)bi * inv63) * 1000.0f;   // /bandwidth
            float w = expf(-0.5f * q * q);
            if (w != 0.0f) atomicAdd(&hist[bi], w);
        }
    }
    __syncthreads();

    if (t < 64) {                                   // one wave handles the 64 bins
        float pdf = hist[t] * (1.0f / 4096.0f);     // mean over vpt
        float s = pdf;
        #pragma unroll
        for (int off = 32; off >= 1; off >>= 1) s += __shfl_xor(s, off, 64);
        float pdfn = pdf / (s + 1e-10f);
        float histo = fminf(pdfn * 4096.0f, 256.0f);    // clip at limit
        float s2 = histo;
        #pragma unroll
        for (int off = 32; off >= 1; off >>= 1) s2 += __shfl_xor(s2, off, 64);
        float clipped = 4096.0f - s2;
        float residual = clipped - floorf(clipped * (1.0f / 64.0f)) * 64.0f;
        float redist = (clipped - residual) * (1.0f / 64.0f);
        float h2 = histo + redist + (((float)t < residual) ? 1.0f : 0.0f);
        float cum = h2;
        #pragma unroll
        for (int off = 1; off < 64; off <<= 1) {
            float p = __shfl_up(cum, off, 64);
            if (t >= off) cum += p;
        }
        cdfbuf[t * 512 + tile] = cum * (63.0f / 4096.0f);
    }
}

// ---------- k2: fold d-axis: T1d[d][n][j][k] = sum_i cdf[n][i][j][k] * M[d][i] ----------
__global__ __launch_bounds__(256) void k2_t1d(const float* __restrict__ cdfbuf,
                                              const float* __restrict__ M,
                                              float* __restrict__ T1d) {
    int idx = blockIdx.x * 256 + threadIdx.x;       // 524288 = 128 * 4096
    int d = idx >> 12;
    int o = idx & 4095;                             // n*64 + j*8 + k
    int n = o >> 6, jk = o & 63;
    const float* m = M + d * 8;
    float s = 0.0f;
    #pragma unroll
    for (int i = 0; i < 8; ++i) s += cdfbuf[n * 512 + i * 64 + jk] * m[i];
    T1d[idx] = s;
}

// ---------- k3: block per (d,h), threads = w row. Fold j -> t2T[k][n] in LDS,
//             then per-voxel 6-tap bin spline. Fully coalesced x/out. ----------
__global__ __launch_bounds__(128) void k3_final(const float* __restrict__ x,
                                                const float* __restrict__ T1d,
                                                const float* __restrict__ M,
                                                float* __restrict__ out,
                                                float* __restrict__ minmax) {
    __shared__ float slice[64 * 65];                // padded [n][j*8+k], stride 65
    __shared__ float t2T[512];                      // [k][n] transposed -> bank = n&31
    __shared__ float red[4];
    int tid = threadIdx.x;                          // = w
    int d = blockIdx.x >> 7;
    int h = blockIdx.x & 127;

    // load the 16KB d-slice of T1d into LDS (coalesced float4, L2-resident)
    const float4* T4 = (const float4*)(T1d + d * 4096);
    #pragma unroll
    for (int r = 0; r < 8; ++r) {
        int i4 = r * 128 + tid;
        float4 v4 = T4[i4];
        int fi = i4 * 4;
        int n = fi >> 6, jk = fi & 63;
        float* p = &slice[n * 65 + jk];
        p[0] = v4.x; p[1] = v4.y; p[2] = v4.z; p[3] = v4.w;
    }
    float mh[8];
    #pragma unroll
    for (int j = 0; j < 8; ++j) mh[j] = M[h * 8 + j];
    float mw[8];
    #pragma unroll
    for (int k = 0; k < 8; ++k) mw[k] = M[tid * 8 + k];
    float v = x[(d * 128 + h) * 128 + tid];
    __syncthreads();

    // fold j with Mh -> t2T[k*64+n]
    #pragma unroll
    for (int p = 0; p < 4; ++p) {
        int o = p * 128 + tid;                      // = k*64 + n
        int k = o >> 6, n = o & 63;
        float s = 0.0f;
        #pragma unroll
        for (int j = 0; j < 8; ++j) s += slice[n * 65 + j * 8 + k] * mh[j];
        t2T[o] = s;
    }
    __syncthreads();

    // bin-axis quintic spline at cb = v*63
    float cb = v * 63.0f;
    int basei = (int)floorf(cb) - 2;
    float acc = 0.0f;
    #pragma unroll
    for (int t = 0; t < 6; ++t) {
        int tap = basei + t;                        // in [-2, 65]
        float wb = bspline5(cb - (float)tap);
        int r = tap & 127;                          // reflect period 128
        int n = r < 64 ? r : 127 - r;
        float s = 0.0f;
        #pragma unroll
        for (int k = 0; k < 8; ++k) s += t2T[k * 64 + n] * mw[k];
        acc += wb * s;
    }
    out[(d * 128 + h) * 128 + tid] = acc;

    // block min/max -> global atomics (values are non-negative)
    float mn = acc, mx = acc;
    #pragma unroll
    for (int off = 32; off >= 1; off >>= 1) {
        mn = fminf(mn, __shfl_xor(mn, off, 64));
        mx = fmaxf(mx, __shfl_xor(mx, off, 64));
    }
    int lane = tid & 63, wv = tid >> 6;
    if (lane == 0) { red[wv * 2] = mn; red[wv * 2 + 1] = mx; }
    __syncthreads();
    if (tid == 0) {
        mn = fminf(red[0], red[2]);
        mx = fmaxf(red[1], red[3]);
        atomicMin((int*)&minmax[0], __float_as_int(mn));
        atomicMax((int*)&minmax[1], __float_as_int(mx));
    }
}

// ---------- k4: global min-max normalize (in place) ----------
__global__ __launch_bounds__(256) void k4_norm(float* __restrict__ out,
                                               const float* __restrict__ minmax) {
    int idx = blockIdx.x * 256 + threadIdx.x;       // 524288 float4s -> 2048 blocks
    float mn = minmax[0], mx = minmax[1];
    float sc = 1.0f / (mx - mn + 1e-10f);
    float4* o4 = (float4*)out;
    float4 val = o4[idx];
    val.x = (val.x - mn) * sc;
    val.y = (val.y - mn) * sc;
    val.z = (val.z - mn) * sc;
    val.w = (val.w - mn) * sc;
    o4[idx] = val;
}

extern "C" void kernel_launch(void* const* d_in, const int* in_sizes, int n_in,
                              void* d_out, int out_size, void* d_ws, size_t ws_size,
                              hipStream_t stream) {
    const float* x = (const float*)d_in[0];
    float* out = (float*)d_out;
    float* ws = (float*)d_ws;
    float* M      = ws + WS_M;
    float* cdfbuf = ws + WS_CDF;
    float* T1d    = ws + WS_T1D;
    float* minmax = ws + WS_MM;

    hipLaunchKernelGGL(k0_axis,  dim3(1),     dim3(128), 0, stream, M, minmax);
    hipLaunchKernelGGL(k1_hist,  dim3(512),   dim3(256), 0, stream, x, cdfbuf);
    hipLaunchKernelGGL(k2_t1d,   dim3(2048),  dim3(256), 0, stream, cdfbuf, M, T1d);
    hipLaunchKernelGGL(k3_final, dim3(16384), dim3(128), 0, stream, x, T1d, M, out, minmax);
    hipLaunchKernelGGL(k4_norm,  dim3(2048),  dim3(256), 0, stream, out, minmax);
}

// Round 3
// 86.760 us; speedup vs baseline: 4.8324x; 4.8100x over previous
//
#include <hip/hip_runtime.h>
#include <math.h>

// CLAHE3D: B=C=1, D=H=W=128, GRID=8x8x8 (tiles 16^3, vpt=4096, nt=512), NB=64,
// bandwidth=0.001, clip=4.0 -> limit=256.
//
// ws layout (floats):
//   M       [128][8]          offset 0        (1024)   axis spline matrix (same for d/h/w)
//   cdfbuf  [64][8][8][8]     offset 1024     (32768)  per-tile CDF, [n][i][j][k]
//   T1d     [128][64][8][8]   offset 33792    (524288) d-axis fold: [d][n][j][k]
//   minmax  [2]               offset 558080   (2)
//   blockmm [16384][2]        offset 558082   (32768)  per-block (min,max) partials

#define WS_M      0
#define WS_CDF    1024
#define WS_T1D    (1024 + 32768)
#define WS_MM     (1024 + 32768 + 524288)
#define WS_BMM    (1024 + 32768 + 524288 + 2)

__device__ __forceinline__ float bspline5(float x) {
    float t = fabsf(x);
    float t2 = t * t, t3 = t2 * t, t4 = t2 * t2, t5 = t4 * t;
    float w0 = 11.0f/20.0f - t2*0.5f + t4*0.25f - t5*(1.0f/12.0f);
    float w1 = 17.0f/40.0f + t*(5.0f/8.0f) - t2*(7.0f/4.0f) + t3*(5.0f/4.0f)
             - t4*(3.0f/8.0f) + t5*(1.0f/24.0f);
    float u = 3.0f - t;
    float w2 = u*u*u*u*u*(1.0f/120.0f);
    return t < 1.0f ? w0 : (t < 2.0f ? w1 : (t < 3.0f ? w2 : 0.0f));
}

// reflect (dct2) boundary for g=8 (period 16): taps in [-3, 10]
__device__ __forceinline__ int reflect16(int t) {
    int r = t & 15;
    return r < 8 ? r : 15 - r;
}

// ---------- k0: axis matrix M[128][8] ----------
__global__ void k0_axis(float* __restrict__ M) {
    int s = threadIdx.x;  // 0..127
    const float step = 8.0625f / 127.0f;            // linspace(-0.53125, 7.53125, 128)
    float c = -0.53125f + (float)s * step;
    float row[8];
    #pragma unroll
    for (int i = 0; i < 8; ++i) row[i] = 0.0f;
    int base = (int)floorf(c) - 2;
    for (int t = 0; t < 6; ++t) {
        int tap = base + t;
        float w = bspline5(c - (float)tap);
        row[reflect16(tap)] += w;
    }
    #pragma unroll
    for (int i = 0; i < 8; ++i) M[s * 8 + i] = row[i];
}

// ---------- k1: per-tile KDE histogram -> clip/redistribute -> CDF ----------
__global__ __launch_bounds__(256) void k1_hist(const float* __restrict__ x,
                                               float* __restrict__ cdfbuf) {
    __shared__ float hist[64];
    int t = threadIdx.x;
    int tile = blockIdx.x;                          // ti*64 + tj*8 + tk
    int ti = tile >> 6, tj = (tile >> 3) & 7, tk = tile & 7;
    if (t < 64) hist[t] = 0.0f;
    __syncthreads();

    const float inv63 = 1.0f / 63.0f;
    int gbase = ((ti * 16) * 128 + tj * 16) * 128 + tk * 16;
    for (int it = 0; it < 16; ++it) {
        int v = it * 256 + t;                       // tile-linear: a=v>>8, b=(v>>4)&15, c=v&15
        int a = v >> 8, b = (v >> 4) & 15, cc = v & 15;
        float val = x[gbase + (a * 128 + b) * 128 + cc];
        float bc = val * 63.0f;
        int b0 = (int)floorf(bc + 0.5f);
        #pragma unroll
        for (int dbi = -1; dbi <= 1; ++dbi) {
            int bi = b0 + dbi;
            if (bi < 0 || bi > 63) continue;
            float q = (val - (float)bi * inv63) * 1000.0f;   // /bandwidth
            float w = expf(-0.5f * q * q);
            if (w != 0.0f) atomicAdd(&hist[bi], w);
        }
    }
    __syncthreads();

    if (t < 64) {                                   // one wave handles the 64 bins
        float pdf = hist[t] * (1.0f / 4096.0f);     // mean over vpt
        float s = pdf;
        #pragma unroll
        for (int off = 32; off >= 1; off >>= 1) s += __shfl_xor(s, off, 64);
        float pdfn = pdf / (s + 1e-10f);
        float histo = fminf(pdfn * 4096.0f, 256.0f);    // clip at limit
        float s2 = histo;
        #pragma unroll
        for (int off = 32; off >= 1; off >>= 1) s2 += __shfl_xor(s2, off, 64);
        float clipped = 4096.0f - s2;
        float residual = clipped - floorf(clipped * (1.0f / 64.0f)) * 64.0f;
        float redist = (clipped - residual) * (1.0f / 64.0f);
        float h2 = histo + redist + (((float)t < residual) ? 1.0f : 0.0f);
        float cum = h2;
        #pragma unroll
        for (int off = 1; off < 64; off <<= 1) {
            float p = __shfl_up(cum, off, 64);
            if (t >= off) cum += p;
        }
        cdfbuf[t * 512 + tile] = cum * (63.0f / 4096.0f);
    }
}

// ---------- k2: fold d-axis: T1d[d][n][j][k] = sum_i cdf[n][i][j][k] * M[d][i] ----------
__global__ __launch_bounds__(256) void k2_t1d(const float* __restrict__ cdfbuf,
                                              const float* __restrict__ M,
                                              float* __restrict__ T1d) {
    int idx = blockIdx.x * 256 + threadIdx.x;       // 524288 = 128 * 4096
    int d = idx >> 12;
    int o = idx & 4095;                             // n*64 + j*8 + k
    int n = o >> 6, jk = o & 63;
    const float* m = M + d * 8;
    float s = 0.0f;
    #pragma unroll
    for (int i = 0; i < 8; ++i) s += cdfbuf[n * 512 + i * 64 + jk] * m[i];
    T1d[idx] = s;
}

// ---------- k3: block per (d,h), threads = w row. Fold j -> t2T[k][n] in LDS,
//             then per-voxel 6-tap bin spline. NO global atomics. ----------
__global__ __launch_bounds__(128) void k3_final(const float* __restrict__ x,
                                                const float* __restrict__ T1d,
                                                const float* __restrict__ M,
                                                float* __restrict__ out,
                                                float* __restrict__ blockmm) {
    __shared__ float slice[64 * 65];                // padded [n][j*8+k], stride 65
    __shared__ float t2T[512];                      // [k][n] transposed -> bank = n&31
    __shared__ float red[4];
    int tid = threadIdx.x;                          // = w
    int d = blockIdx.x >> 7;
    int h = blockIdx.x & 127;

    // load the 16KB d-slice of T1d into LDS (coalesced float4, L2-resident)
    const float4* T4 = (const float4*)(T1d + d * 4096);
    #pragma unroll
    for (int r = 0; r < 8; ++r) {
        int i4 = r * 128 + tid;
        float4 v4 = T4[i4];
        int fi = i4 * 4;
        int n = fi >> 6, jk = fi & 63;
        float* p = &slice[n * 65 + jk];
        p[0] = v4.x; p[1] = v4.y; p[2] = v4.z; p[3] = v4.w;
    }
    float mh[8];
    #pragma unroll
    for (int j = 0; j < 8; ++j) mh[j] = M[h * 8 + j];
    float mw[8];
    #pragma unroll
    for (int k = 0; k < 8; ++k) mw[k] = M[tid * 8 + k];
    float v = x[(d * 128 + h) * 128 + tid];
    __syncthreads();

    // fold j with Mh -> t2T[k*64+n]
    #pragma unroll
    for (int p = 0; p < 4; ++p) {
        int o = p * 128 + tid;                      // = k*64 + n
        int k = o >> 6, n = o & 63;
        float s = 0.0f;
        #pragma unroll
        for (int j = 0; j < 8; ++j) s += slice[n * 65 + j * 8 + k] * mh[j];
        t2T[o] = s;
    }
    __syncthreads();

    // bin-axis quintic spline at cb = v*63
    float cb = v * 63.0f;
    int basei = (int)floorf(cb) - 2;
    float acc = 0.0f;
    #pragma unroll
    for (int t = 0; t < 6; ++t) {
        int tap = basei + t;                        // in [-2, 65]
        float wb = bspline5(cb - (float)tap);
        int r = tap & 127;                          // reflect period 128
        int n = r < 64 ? r : 127 - r;
        float s = 0.0f;
        #pragma unroll
        for (int k = 0; k < 8; ++k) s += t2T[k * 64 + n] * mw[k];
        acc += wb * s;
    }
    out[(d * 128 + h) * 128 + tid] = acc;

    // block min/max -> plain per-block store (no contended atomics)
    float mn = acc, mx = acc;
    #pragma unroll
    for (int off = 32; off >= 1; off >>= 1) {
        mn = fminf(mn, __shfl_xor(mn, off, 64));
        mx = fmaxf(mx, __shfl_xor(mx, off, 64));
    }
    int lane = tid & 63, wv = tid >> 6;
    if (lane == 0) { red[wv * 2] = mn; red[wv * 2 + 1] = mx; }
    __syncthreads();
    if (tid == 0) {
        mn = fminf(red[0], red[2]);
        mx = fmaxf(red[1], red[3]);
        ((float2*)blockmm)[blockIdx.x] = make_float2(mn, mx);
    }
}

// ---------- k3b: reduce 16384 per-block partials -> minmax[2] (single block) ----------
__global__ __launch_bounds__(256) void k3b_reduce(const float* __restrict__ blockmm,
                                                  float* __restrict__ minmax) {
    __shared__ float smn[4], smx[4];
    int t = threadIdx.x;
    float mn = 3.4e38f, mx = -3.4e38f;
    const float2* bm = (const float2*)blockmm;
    for (int i = t; i < 16384; i += 256) {
        float2 v = bm[i];
        mn = fminf(mn, v.x);
        mx = fmaxf(mx, v.y);
    }
    #pragma unroll
    for (int off = 32; off >= 1; off >>= 1) {
        mn = fminf(mn, __shfl_xor(mn, off, 64));
        mx = fmaxf(mx, __shfl_xor(mx, off, 64));
    }
    int lane = t & 63, wv = t >> 6;
    if (lane == 0) { smn[wv] = mn; smx[wv] = mx; }
    __syncthreads();
    if (t == 0) {
        mn = fminf(fminf(smn[0], smn[1]), fminf(smn[2], smn[3]));
        mx = fmaxf(fmaxf(smx[0], smx[1]), fmaxf(smx[2], smx[3]));
        minmax[0] = mn;
        minmax[1] = mx;
    }
}

// ---------- k4: global min-max normalize (in place) ----------
__global__ __launch_bounds__(256) void k4_norm(float* __restrict__ out,
                                               const float* __restrict__ minmax) {
    int idx = blockIdx.x * 256 + threadIdx.x;       // 524288 float4s -> 2048 blocks
    float mn = minmax[0], mx = minmax[1];
    float sc = 1.0f / (mx - mn + 1e-10f);
    float4* o4 = (float4*)out;
    float4 val = o4[idx];
    val.x = (val.x - mn) * sc;
    val.y = (val.y - mn) * sc;
    val.z = (val.z - mn) * sc;
    val.w = (val.w - mn) * sc;
    o4[idx] = val;
}

extern "C" void kernel_launch(void* const* d_in, const int* in_sizes, int n_in,
                              void* d_out, int out_size, void* d_ws, size_t ws_size,
                              hipStream_t stream) {
    const float* x = (const float*)d_in[0];
    float* out = (float*)d_out;
    float* ws = (float*)d_ws;
    float* M       = ws + WS_M;
    float* cdfbuf  = ws + WS_CDF;
    float* T1d     = ws + WS_T1D;
    float* minmax  = ws + WS_MM;
    float* blockmm = ws + WS_BMM;

    hipLaunchKernelGGL(k0_axis,    dim3(1),     dim3(128), 0, stream, M);
    hipLaunchKernelGGL(k1_hist,    dim3(512),   dim3(256), 0, stream, x, cdfbuf);
    hipLaunchKernelGGL(k2_t1d,     dim3(2048),  dim3(256), 0, stream, cdfbuf, M, T1d);
    hipLaunchKernelGGL(k3_final,   dim3(16384), dim3(128), 0, stream, x, T1d, M, out, blockmm);
    hipLaunchKernelGGL(k3b_reduce, dim3(1),     dim3(256), 0, stream, blockmm, minmax);
    hipLaunchKernelGGL(k4_norm,    dim3(2048),  dim3(256), 0, stream, out, minmax);
}

// Round 4
// 52.201 us; speedup vs baseline: 8.0317x; 1.6620x over previous
//
#include <hip/hip_runtime.h>
#include <math.h>

// CLAHE3D: B=C=1, D=H=W=128, GRID=8x8x8 (tiles 16^3, vpt=4096, nt=512), NB=64,
// bandwidth=0.001, clip=4.0 -> limit=256.
//
// ws layout (floats):
//   M       [128][8]          offset 0        (1024)   axis spline matrix (same for d/h/w)
//   cdf     [8][64][64]       offset 1024     (32768)  per-tile CDF, [i][jk][n]  (n innermost!)
//   T1d     [128][64][64]     offset 33792    (524288) d-axis fold: [d][jk][n]
//   minmax  [2]               offset 558080   (2)
//   blockmm [8192][2]         offset 558082   (16384)  per-block (min,max) partials

#define WS_M      0
#define WS_CDF    1024
#define WS_T1D    (1024 + 32768)
#define WS_MM     (1024 + 32768 + 524288)
#define WS_BMM    (WS_MM + 2)

__device__ __forceinline__ float bspline5(float x) {
    float t = fabsf(x);
    float t2 = t * t, t3 = t2 * t, t4 = t2 * t2, t5 = t4 * t;
    float w0 = 11.0f/20.0f - t2*0.5f + t4*0.25f - t5*(1.0f/12.0f);
    float w1 = 17.0f/40.0f + t*(5.0f/8.0f) - t2*(7.0f/4.0f) + t3*(5.0f/4.0f)
             - t4*(3.0f/8.0f) + t5*(1.0f/24.0f);
    float u = 3.0f - t;
    float w2 = u*u*u*u*u*(1.0f/120.0f);
    return t < 1.0f ? w0 : (t < 2.0f ? w1 : (t < 3.0f ? w2 : 0.0f));
}

// Branch-free quintic tap weights for u = frac(cb) in [0,1):
// tap tt has |x| = |u + 2 - tt|, each tap lives in one fixed spline piece.
__device__ __forceinline__ void quintic_w(float u, float wb[6]) {
    float u2 = u*u, u4 = u2*u2, u5 = u4*u;
    float v = 1.0f - u;
    float v2 = v*v, v4 = v2*v2, v5 = v4*v;
    wb[0] = v5 * (1.0f/120.0f);
    wb[5] = u5 * (1.0f/120.0f);
    {
        float t = u + 1.0f;
        float t2 = t*t, t3 = t2*t, t4 = t2*t2, t5 = t4*t;
        wb[1] = 17.0f/40.0f + t*(5.0f/8.0f) - t2*(7.0f/4.0f) + t3*(5.0f/4.0f)
              - t4*(3.0f/8.0f) + t5*(1.0f/24.0f);
    }
    {
        float t = 2.0f - u;
        float t2 = t*t, t3 = t2*t, t4 = t2*t2, t5 = t4*t;
        wb[4] = 17.0f/40.0f + t*(5.0f/8.0f) - t2*(7.0f/4.0f) + t3*(5.0f/4.0f)
              - t4*(3.0f/8.0f) + t5*(1.0f/24.0f);
    }
    wb[2] = 11.0f/20.0f - u2*0.5f + u4*0.25f - u5*(1.0f/12.0f);
    wb[3] = 11.0f/20.0f - v2*0.5f + v4*0.25f - v5*(1.0f/12.0f);
}

// reflect (dct2) boundary for g=8 (period 16)
__device__ __forceinline__ int reflect16(int t) {
    int r = t & 15;
    return r < 8 ? r : 15 - r;
}

// ---------- k0: axis matrix M[128][8] ----------
__global__ void k0_axis(float* __restrict__ M) {
    int s = threadIdx.x;  // 0..127
    const float step = 8.0625f / 127.0f;            // linspace(-0.53125, 7.53125, 128)
    float c = -0.53125f + (float)s * step;
    float row[8];
    #pragma unroll
    for (int i = 0; i < 8; ++i) row[i] = 0.0f;
    int base = (int)floorf(c) - 2;
    for (int t = 0; t < 6; ++t) {
        int tap = base + t;
        float w = bspline5(c - (float)tap);
        row[reflect16(tap)] += w;
    }
    #pragma unroll
    for (int i = 0; i < 8; ++i) M[s * 8 + i] = row[i];
}

// ---------- k1: per-tile KDE histogram -> clip/redistribute -> CDF ----------
// bandwidth=0.001 << bin spacing 1/63: only the nearest bin gets a weight
// above ~e^-31 (2nd-nearest <= 2e-14, 3rd underflows fp32 exactly as in jnp).
__global__ __launch_bounds__(256) void k1_hist(const float* __restrict__ x,
                                               float* __restrict__ cdfbuf) {
    __shared__ float hist[256];                     // 4 waves x 64 bins
    int t = threadIdx.x;
    int wv = t >> 6;
    int tile = blockIdx.x;                          // i*64 + j*8 + k
    int ti = tile >> 6, tj = (tile >> 3) & 7, tk = tile & 7;
    hist[t] = 0.0f;
    __syncthreads();

    const float inv63 = 1.0f / 63.0f;
    int gbase4 = (((ti * 16) * 128 + tj * 16) * 128 + tk * 16) >> 2;
    const float4* x4 = (const float4*)x;
    #pragma unroll
    for (int it = 0; it < 4; ++it) {
        int vi = it * 256 + t;                      // 1024 float4 per tile
        int c4 = vi & 3, b = (vi >> 2) & 15, a = vi >> 6;
        float4 v4 = x4[gbase4 + a * 4096 + b * 32 + c4];
        float vals[4] = {v4.x, v4.y, v4.z, v4.w};
        #pragma unroll
        for (int m = 0; m < 4; ++m) {
            float val = vals[m];
            int b0 = (int)floorf(val * 63.0f + 0.5f);   // nearest bin, in [0,63]
            float q = (val - (float)b0 * inv63) * 1000.0f;
            float w = __expf(-0.5f * q * q);
            atomicAdd(&hist[wv * 64 + b0], w);
        }
    }
    __syncthreads();

    if (t < 64) {                                   // one wave: clip/redistribute/CDF
        float pdf = (hist[t] + hist[64 + t] + hist[128 + t] + hist[192 + t])
                    * (1.0f / 4096.0f);
        float s = pdf;
        #pragma unroll
        for (int off = 32; off >= 1; off >>= 1) s += __shfl_xor(s, off, 64);
        float pdfn = pdf / (s + 1e-10f);
        float histo = fminf(pdfn * 4096.0f, 256.0f);
        float s2 = histo;
        #pragma unroll
        for (int off = 32; off >= 1; off >>= 1) s2 += __shfl_xor(s2, off, 64);
        float clipped = 4096.0f - s2;
        float residual = clipped - floorf(clipped * (1.0f / 64.0f)) * 64.0f;
        float redist = (clipped - residual) * (1.0f / 64.0f);
        float h2 = histo + redist + (((float)t < residual) ? 1.0f : 0.0f);
        float cum = h2;
        #pragma unroll
        for (int off = 1; off < 64; off <<= 1) {
            float p = __shfl_up(cum, off, 64);
            if (t >= off) cum += p;
        }
        cdfbuf[tile * 64 + t] = cum * (63.0f / 4096.0f);    // [i][jk][n], coalesced
    }
}

// ---------- k2: fold d: T1d[d][jk][n] = sum_i cdf[i][jk][n] * M[d][i] (float4) ----------
__global__ __launch_bounds__(256) void k2_t1d(const float* __restrict__ cdfbuf,
                                              const float* __restrict__ M,
                                              float* __restrict__ T1d) {
    int i4 = blockIdx.x * 256 + threadIdx.x;        // 131072 float4 ids
    int d = i4 >> 10;                               // 1024 float4 per d
    int o4 = i4 & 1023;
    const float4* c4 = (const float4*)cdfbuf;
    float md[8];
    #pragma unroll
    for (int i = 0; i < 8; ++i) md[i] = M[d * 8 + i];
    float4 s = make_float4(0.f, 0.f, 0.f, 0.f);
    #pragma unroll
    for (int i = 0; i < 8; ++i) {
        float4 c = c4[i * 1024 + o4];
        s.x += c.x * md[i]; s.y += c.y * md[i];
        s.z += c.z * md[i]; s.w += c.w * md[i];
    }
    ((float4*)T1d)[i4] = s;
}

// ---------- k3: 256 threads = 2 (d,h) rows. j-fold straight from L1/L2 into
//             t2T LDS, then branch-free 6-tap bin spline. ----------
__global__ __launch_bounds__(256) void k3_final(const float* __restrict__ x,
                                                const float* __restrict__ T1d,
                                                const float* __restrict__ M,
                                                float* __restrict__ out,
                                                float* __restrict__ blockmm) {
    __shared__ float t2T[2][512];                   // per group: [k][n]
    __shared__ float smn[4], smx[4];
    int tid = threadIdx.x;
    int g = tid >> 7, lt = tid & 127;               // group, lane-in-group (= w)
    int pair = blockIdx.x * 2 + g;                  // d*128 + h
    int d = pair >> 7, h = pair & 127;

    float mh[8];
    #pragma unroll
    for (int j = 0; j < 8; ++j) mh[j] = M[h * 8 + j];
    float mw[8];
    #pragma unroll
    for (int k = 0; k < 8; ++k) mw[k] = M[lt * 8 + k];

    // j-fold: t2T[k][n] = sum_j T1d[d][j*8+k][n] * mh[j]; coalesced 256B reads
    const float* T1s = T1d + d * 4096;
    #pragma unroll
    for (int p = 0; p < 4; ++p) {
        int o = p * 128 + lt;                       // k*64 + n
        const float* bp = T1s + o;                  // (k*64+n); +j*512 walks j
        float s = 0.0f;
        #pragma unroll
        for (int j = 0; j < 8; ++j) s += bp[j * 512] * mh[j];
        t2T[g][o] = s;
    }
    float v = x[pair * 128 + lt];
    __syncthreads();

    // bin-axis quintic spline at cb = v*63 (branch-free weights)
    float cb = v * 63.0f;
    float fl = floorf(cb);
    int basei = (int)fl - 2;
    float wb[6];
    quintic_w(cb - fl, wb);
    float acc = 0.0f;
    #pragma unroll
    for (int tt = 0; tt < 6; ++tt) {
        int tap = basei + tt;                       // in [-2, 66]
        int r = tap & 127;                          // reflect period 128
        int n = r < 64 ? r : 127 - r;
        const float* t2 = &t2T[g][n];
        float s = 0.0f;
        #pragma unroll
        for (int k = 0; k < 8; ++k) s += t2[k * 64] * mw[k];
        acc += wb[tt] * s;
    }
    out[pair * 128 + lt] = acc;

    // block min/max -> one float2 per block
    float mn = acc, mx = acc;
    #pragma unroll
    for (int off = 32; off >= 1; off >>= 1) {
        mn = fminf(mn, __shfl_xor(mn, off, 64));
        mx = fmaxf(mx, __shfl_xor(mx, off, 64));
    }
    int lane = tid & 63, wv = tid >> 6;
    if (lane == 0) { smn[wv] = mn; smx[wv] = mx; }
    __syncthreads();
    if (tid == 0) {
        mn = fminf(fminf(smn[0], smn[1]), fminf(smn[2], smn[3]));
        mx = fmaxf(fmaxf(smx[0], smx[1]), fmaxf(smx[2], smx[3]));
        ((float2*)blockmm)[blockIdx.x] = make_float2(mn, mx);
    }
}

// ---------- k3b: reduce 8192 per-block partials -> minmax[2] (single block) ----------
__global__ __launch_bounds__(1024) void k3b_reduce(const float* __restrict__ blockmm,
                                                   float* __restrict__ minmax) {
    __shared__ float smn[16], smx[16];
    int t = threadIdx.x;
    float mn = 3.4e38f, mx = -3.4e38f;
    const float2* bm = (const float2*)blockmm;
    for (int i = t; i < 8192; i += 1024) {
        float2 v = bm[i];
        mn = fminf(mn, v.x);
        mx = fmaxf(mx, v.y);
    }
    #pragma unroll
    for (int off = 32; off >= 1; off >>= 1) {
        mn = fminf(mn, __shfl_xor(mn, off, 64));
        mx = fmaxf(mx, __shfl_xor(mx, off, 64));
    }
    int lane = t & 63, wv = t >> 6;
    if (lane == 0) { smn[wv] = mn; smx[wv] = mx; }
    __syncthreads();
    if (t == 0) {
        #pragma unroll
        for (int i = 1; i < 16; ++i) {
            smn[0] = fminf(smn[0], smn[i]);
            smx[0] = fmaxf(smx[0], smx[i]);
        }
        minmax[0] = smn[0];
        minmax[1] = smx[0];
    }
}

// ---------- k4: global min-max normalize (in place) ----------
__global__ __launch_bounds__(256) void k4_norm(float* __restrict__ out,
                                               const float* __restrict__ minmax) {
    int idx = blockIdx.x * 256 + threadIdx.x;       // 524288 float4s -> 2048 blocks
    float mn = minmax[0], mx = minmax[1];
    float sc = 1.0f / (mx - mn + 1e-10f);
    float4* o4 = (float4*)out;
    float4 val = o4[idx];
    val.x = (val.x - mn) * sc;
    val.y = (val.y - mn) * sc;
    val.z = (val.z - mn) * sc;
    val.w = (val.w - mn) * sc;
    o4[idx] = val;
}

extern "C" void kernel_launch(void* const* d_in, const int* in_sizes, int n_in,
                              void* d_out, int out_size, void* d_ws, size_t ws_size,
                              hipStream_t stream) {
    const float* x = (const float*)d_in[0];
    float* out = (float*)d_out;
    float* ws = (float*)d_ws;
    float* M       = ws + WS_M;
    float* cdfbuf  = ws + WS_CDF;
    float* T1d     = ws + WS_T1D;
    float* minmax  = ws + WS_MM;
    float* blockmm = ws + WS_BMM;

    hipLaunchKernelGGL(k0_axis,    dim3(1),    dim3(128),  0, stream, M);
    hipLaunchKernelGGL(k1_hist,    dim3(512),  dim3(256),  0, stream, x, cdfbuf);
    hipLaunchKernelGGL(k2_t1d,     dim3(512),  dim3(256),  0, stream, cdfbuf, M, T1d);
    hipLaunchKernelGGL(k3_final,   dim3(8192), dim3(256),  0, stream, x, T1d, M, out, blockmm);
    hipLaunchKernelGGL(k3b_reduce, dim3(1),    dim3(1024), 0, stream, blockmm, minmax);
    hipLaunchKernelGGL(k4_norm,    dim3(2048), dim3(256),  0, stream, out, minmax);
}